// Round 6
// baseline (551.059 us; speedup 1.0000x reference)
//
#include <hip/hip_runtime.h>

typedef __attribute__((ext_vector_type(4))) float f32x4;
typedef __attribute__((ext_vector_type(8))) short s16x8;
typedef __attribute__((ext_vector_type(4))) short s16x4;

#define B_ 128
#define L_ 256
#define C_ 256
#define NH 8
#define HD 32
#define MTOT (B_*L_)       // 32768
#define NQKV 768
#define QS (B_*NH*L_*HD)   // 8388608 elements per q/k/v buffer

__device__ __forceinline__ unsigned short f2bf(float f) {
    unsigned u = __builtin_bit_cast(unsigned, f);
    u += 0x7fffu + ((u >> 16) & 1u);
    return (unsigned short)(u >> 16);
}
__device__ __forceinline__ float bf2f(unsigned short s) {
    return __builtin_bit_cast(float, (unsigned)s << 16);
}

// ---------------------------------------------------------------------------
// K1: QKV GEMM.  x[32768][256] (fp32) @ w_qkv[256][768] (fp32) + b ->
//     q/k/v bf16 in ws, layout [b][h][l][d]
// ---------------------------------------------------------------------------
__global__ __launch_bounds__(256) void qkv_gemm(
    const float* __restrict__ x, const float* __restrict__ w,
    const float* __restrict__ bias, unsigned short* __restrict__ qkv) {
    __shared__ unsigned short lA[128][40];   // [row][k], pad 32->40
    __shared__ unsigned short lB[128][40];   // [col][k]
    const int t  = threadIdx.x;
    const int m0 = blockIdx.y * 128;
    const int n0 = blockIdx.x * 128;
    const int lane = t & 63, wv = t >> 6;
    const int wr = (wv >> 1) * 64, wc = (wv & 1) * 64;
    const int lr = lane & 15, lg = lane >> 4;

    f32x4 acc[4][4];
#pragma unroll
    for (int i = 0; i < 4; i++)
#pragma unroll
        for (int j = 0; j < 4; j++) acc[i][j] = f32x4{0.f, 0.f, 0.f, 0.f};

    for (int k0 = 0; k0 < 256; k0 += 32) {
#pragma unroll
        for (int i = 0; i < 4; i++) {               // A: 128x32 fp32 -> bf16
            int idx = t + i * 256;
            int row = idx >> 3, c4 = (idx & 7) << 2;
            const f32x4 v = *(const f32x4*)(x + (size_t)(m0 + row) * 256 + k0 + c4);
            lA[row][c4 + 0] = f2bf(v.x); lA[row][c4 + 1] = f2bf(v.y);
            lA[row][c4 + 2] = f2bf(v.z); lA[row][c4 + 3] = f2bf(v.w);
        }
#pragma unroll
        for (int i = 0; i < 4; i++) {               // B: 32x128 fp32 -> bf16 transposed
            int idx = t + i * 256;
            int kk = idx >> 5, n4 = (idx & 31) << 2;
            const f32x4 v = *(const f32x4*)(w + (size_t)(k0 + kk) * NQKV + n0 + n4);
            lB[n4 + 0][kk] = f2bf(v.x); lB[n4 + 1][kk] = f2bf(v.y);
            lB[n4 + 2][kk] = f2bf(v.z); lB[n4 + 3][kk] = f2bf(v.w);
        }
        __syncthreads();
        s16x8 af[4], bf[4];
#pragma unroll
        for (int rt = 0; rt < 4; rt++) af[rt] = *(const s16x8*)(&lA[wr + rt * 16 + lr][lg * 8]);
#pragma unroll
        for (int ct = 0; ct < 4; ct++) bf[ct] = *(const s16x8*)(&lB[wc + ct * 16 + lr][lg * 8]);
#pragma unroll
        for (int rt = 0; rt < 4; rt++)
#pragma unroll
            for (int ct = 0; ct < 4; ct++)
                acc[rt][ct] = __builtin_amdgcn_mfma_f32_16x16x32_bf16(af[rt], bf[ct], acc[rt][ct], 0, 0, 0);
        __syncthreads();
    }
#pragma unroll
    for (int rt = 0; rt < 4; rt++)
#pragma unroll
        for (int ct = 0; ct < 4; ct++)
#pragma unroll
            for (int r = 0; r < 4; r++) {
                int gm = m0 + wr + rt * 16 + lg * 4 + r;
                int gn = n0 + wc + ct * 16 + lr;
                float val = acc[rt][ct][r] + bias[gn];
                int which = gn >> 8, h = (gn >> 5) & 7, d = gn & 31;
                int b = gm >> 8, ll = gm & 255;
                qkv[(size_t)which * QS + ((((size_t)b * NH + h) * L_ + ll) << 5) + d] = f2bf(val);
            }
}

// ---------------------------------------------------------------------------
// K2: fused attention per (b,h).  S=qk^T (MFMA), +mask, softmax (wave-parallel),
//     attn dump (coalesced fp32), PV (MFMA), fused LePE conv, O -> ws bf16.
// ---------------------------------------------------------------------------
__global__ __launch_bounds__(256) void attn_fused(
    const unsigned short* __restrict__ qw, const unsigned short* __restrict__ kw,
    const unsigned short* __restrict__ vw, const float* __restrict__ mask,
    const float* __restrict__ convw, const float* __restrict__ convb,
    float* __restrict__ attn_out, unsigned short* __restrict__ Ow) {
    __shared__ unsigned short lvT[32][264];  // v transposed: [d][l]
    __shared__ unsigned short lP[64][264];   // P bf16: [row(64)][col(256)]
    const int t = threadIdx.x;
    const int bh = blockIdx.x;
    const int b = bh >> 3, h = bh & 7;
    const size_t base = (size_t)bh * (L_ * HD);
    const int lane = t & 63, wv = t >> 6;
    const int lr = lane & 15, lg = lane >> 4;
    const float scale = 0.17677669529663687f;  // 32^-0.5

    {   // stage v transposed into LDS
        const unsigned short* vrow = vw + base + (size_t)t * HD;
#pragma unroll
        for (int i = 0; i < 4; i++) {
            s16x8 v8 = *(const s16x8*)(vrow + i * 8);
#pragma unroll
            for (int j = 0; j < 8; j++) lvT[i * 8 + j][t] = (unsigned short)v8[j];
        }
    }
    __syncthreads();

    const float* mwin = mask + (size_t)(b & 63) * (256 * 256);

    for (int it = 0; it < 4; it++) {
        const int row0 = it * 64 + wv * 16;
        // ---- S = q @ k^T  (K=32, one MFMA per 16x16 tile)
        s16x8 qa = *(const s16x8*)(qw + base + (size_t)(row0 + lr) * HD + lg * 8);
        f32x4 sc[16];
        const f32x4 zero4 = f32x4{0.f, 0.f, 0.f, 0.f};
#pragma unroll
        for (int ct = 0; ct < 16; ct++) {
            s16x8 kb = *(const s16x8*)(kw + base + (size_t)(ct * 16 + lr) * HD + lg * 8);
            sc[ct] = __builtin_amdgcn_mfma_f32_16x16x32_bf16(qa, kb, zero4, 0, 0, 0);
        }
        // ---- scale + mask
        const int rbase = row0 + lg * 4;
#pragma unroll
        for (int r = 0; r < 4; r++) {
            const float* mrow = mwin + (size_t)(rbase + r) * 256 + lr;
#pragma unroll
            for (int ct = 0; ct < 16; ct++)
                sc[ct][r] = sc[ct][r] * scale + mrow[ct * 16];
        }
        // ---- softmax per row (row lives in 16 lanes sharing lg)
#pragma unroll
        for (int r = 0; r < 4; r++) {
            float mx = -1e30f;
#pragma unroll
            for (int ct = 0; ct < 16; ct++) mx = fmaxf(mx, sc[ct][r]);
#pragma unroll
            for (int off = 1; off < 16; off <<= 1) mx = fmaxf(mx, __shfl_xor(mx, off, 64));
            float sum = 0.f;
#pragma unroll
            for (int ct = 0; ct < 16; ct++) {
                float e = __expf(sc[ct][r] - mx);
                sc[ct][r] = e; sum += e;
            }
#pragma unroll
            for (int off = 1; off < 16; off <<= 1) sum += __shfl_xor(sum, off, 64);
            float inv = 1.f / sum;
#pragma unroll
            for (int ct = 0; ct < 16; ct++) sc[ct][r] *= inv;
        }
        // ---- P -> LDS (bf16)
#pragma unroll
        for (int ct = 0; ct < 16; ct++)
#pragma unroll
            for (int r = 0; r < 4; r++)
                lP[wv * 16 + lg * 4 + r][ct * 16 + lr] = f2bf(sc[ct][r]);
        __syncthreads();
        // ---- coalesced attn dump (fp32 from bf16 P)
        {
            float* aout = attn_out + ((size_t)bh * 256 + it * 64) * 256;
#pragma unroll
            for (int i = 0; i < 16; i++) {
                int idx = t + i * 256;
                int r = idx >> 6, c4 = (idx & 63) << 2;
                s16x4 p4 = *(const s16x4*)(&lP[r][c4]);
                f32x4 o = f32x4{bf2f((unsigned short)p4[0]), bf2f((unsigned short)p4[1]),
                                bf2f((unsigned short)p4[2]), bf2f((unsigned short)p4[3])};
                *(f32x4*)(aout + (size_t)r * 256 + c4) = o;
            }
        }
        // ---- PV: O(16x32) = P(16x256) @ v(256x32)
        f32x4 oacc[2];
        oacc[0] = f32x4{0.f, 0.f, 0.f, 0.f};
        oacc[1] = f32x4{0.f, 0.f, 0.f, 0.f};
#pragma unroll
        for (int ks = 0; ks < 8; ks++) {
            s16x8 pa = *(const s16x8*)(&lP[wv * 16 + lr][ks * 32 + lg * 8]);
#pragma unroll
            for (int dt = 0; dt < 2; dt++) {
                s16x8 vb = *(const s16x8*)(&lvT[dt * 16 + lr][ks * 32 + lg * 8]);
                oacc[dt] = __builtin_amdgcn_mfma_f32_16x16x32_bf16(pa, vb, oacc[dt], 0, 0, 0);
            }
        }
        // ---- LePE (depthwise 3x3 on v as (C,16,16)) + write O
#pragma unroll
        for (int dt = 0; dt < 2; dt++) {
            int d = dt * 16 + lr;
            int c = h * 32 + d;
            const float* w9 = convw + c * 9;
#pragma unroll
            for (int r = 0; r < 4; r++) {
                int lglob = row0 + lg * 4 + r;
                int y = lglob >> 4, xx = lglob & 15;
                float lep = convb[c];
#pragma unroll
                for (int dy = -1; dy <= 1; dy++) {
                    int yy = y + dy;
                    if (yy < 0 || yy > 15) continue;
#pragma unroll
                    for (int dx = -1; dx <= 1; dx++) {
                        int x2 = xx + dx;
                        if (x2 < 0 || x2 > 15) continue;
                        lep += w9[(dy + 1) * 3 + (dx + 1)] * bf2f(lvT[d][yy * 16 + x2]);
                    }
                }
                float ov = oacc[dt][r] + lep;
                Ow[((size_t)b * L_ + lglob) * C_ + c] = f2bf(ov);
            }
        }
        __syncthreads();   // protect lP before next iteration
    }
}

// ---------------------------------------------------------------------------
// K3: projection GEMM.  O[32768][256] (bf16 ws) @ w_proj[256][256] + b -> out fp32
// ---------------------------------------------------------------------------
__global__ __launch_bounds__(256) void proj_gemm(
    const unsigned short* __restrict__ A, const float* __restrict__ w,
    const float* __restrict__ bias, float* __restrict__ out) {
    __shared__ unsigned short lA[128][40];
    __shared__ unsigned short lB[128][40];
    const int t  = threadIdx.x;
    const int m0 = blockIdx.y * 128;
    const int n0 = blockIdx.x * 128;
    const int lane = t & 63, wv = t >> 6;
    const int wr = (wv >> 1) * 64, wc = (wv & 1) * 64;
    const int lr = lane & 15, lg = lane >> 4;

    f32x4 acc[4][4];
#pragma unroll
    for (int i = 0; i < 4; i++)
#pragma unroll
        for (int j = 0; j < 4; j++) acc[i][j] = f32x4{0.f, 0.f, 0.f, 0.f};

    for (int k0 = 0; k0 < 256; k0 += 32) {
#pragma unroll
        for (int i = 0; i < 2; i++) {              // A: 128x32 bf16
            int idx = t + i * 256;
            int row = idx >> 2, c8 = (idx & 3) << 3;
            s16x8 v8 = *(const s16x8*)(A + (size_t)(m0 + row) * 256 + k0 + c8);
            *(s16x8*)(&lA[row][c8]) = v8;
        }
#pragma unroll
        for (int i = 0; i < 4; i++) {              // B: 32x128 fp32 -> bf16 transposed
            int idx = t + i * 256;
            int kk = idx >> 5, n4 = (idx & 31) << 2;
            const f32x4 v = *(const f32x4*)(w + (size_t)(k0 + kk) * 256 + n0 + n4);
            lB[n4 + 0][kk] = f2bf(v.x); lB[n4 + 1][kk] = f2bf(v.y);
            lB[n4 + 2][kk] = f2bf(v.z); lB[n4 + 3][kk] = f2bf(v.w);
        }
        __syncthreads();
        s16x8 af[4], bf[4];
#pragma unroll
        for (int rt = 0; rt < 4; rt++) af[rt] = *(const s16x8*)(&lA[wr + rt * 16 + lr][lg * 8]);
#pragma unroll
        for (int ct = 0; ct < 4; ct++) bf[ct] = *(const s16x8*)(&lB[wc + ct * 16 + lr][lg * 8]);
#pragma unroll
        for (int rt = 0; rt < 4; rt++)
#pragma unroll
            for (int ct = 0; ct < 4; ct++)
                acc[rt][ct] = __builtin_amdgcn_mfma_f32_16x16x32_bf16(af[rt], bf[ct], acc[rt][ct], 0, 0, 0);
        __syncthreads();
    }
#pragma unroll
    for (int rt = 0; rt < 4; rt++)
#pragma unroll
        for (int ct = 0; ct < 4; ct++)
#pragma unroll
            for (int r = 0; r < 4; r++) {
                int gm = m0 + wr + rt * 16 + lg * 4 + r;
                int gn = n0 + wc + ct * 16 + lr;
                out[(size_t)gm * 256 + gn] = acc[rt][ct][r] + bias[gn];
            }
}

// ---------------------------------------------------------------------------
extern "C" void kernel_launch(void* const* d_in, const int* in_sizes, int n_in,
                              void* d_out, int out_size, void* d_ws, size_t ws_size,
                              hipStream_t stream) {
    const float* x      = (const float*)d_in[0];
    const float* mask   = (const float*)d_in[1];
    const float* w_qkv  = (const float*)d_in[2];
    const float* b_qkv  = (const float*)d_in[3];
    const float* conv_w = (const float*)d_in[4];
    const float* conv_b = (const float*)d_in[5];
    const float* w_proj = (const float*)d_in[6];
    const float* b_proj = (const float*)d_in[7];

    float* out  = (float*)d_out;
    float* attn = out + (size_t)MTOT * C_;          // second output, concatenated

    unsigned short* ws = (unsigned short*)d_ws;     // 4 x QS bf16 = 64 MB
    unsigned short* qw = ws;
    unsigned short* kw = ws + (size_t)QS;
    unsigned short* vw = ws + (size_t)2 * QS;
    unsigned short* Ow = ws + (size_t)3 * QS;

    qkv_gemm<<<dim3(6, 256), 256, 0, stream>>>(x, w_qkv, b_qkv, qw);
    attn_fused<<<dim3(1024), 256, 0, stream>>>(qw, kw, vw, mask, conv_w, conv_b, attn, Ow);
    proj_gemm<<<dim3(2, 256), 256, 0, stream>>>(Ow, w_proj, b_proj, out);
}

// Round 7
// 496.786 us; speedup vs baseline: 1.1092x; 1.1092x over previous
//
#include <hip/hip_runtime.h>

typedef __attribute__((ext_vector_type(4))) float f32x4;
typedef __attribute__((ext_vector_type(8))) short s16x8;
typedef __attribute__((ext_vector_type(4))) short s16x4;

#define B_ 128
#define L_ 256
#define C_ 256
#define NH 8
#define HD 32
#define MTOT (B_*L_)       // 32768
#define NQKV 768
#define QS (B_*NH*L_*HD)   // 8388608 elements per q/k/v buffer

__device__ __forceinline__ unsigned short f2bf(float f) {
    unsigned u = __builtin_bit_cast(unsigned, f);
    u += 0x7fffu + ((u >> 16) & 1u);
    return (unsigned short)(u >> 16);
}
__device__ __forceinline__ float bf2f(unsigned short s) {
    return __builtin_bit_cast(float, (unsigned)s << 16);
}

// ---------------------------------------------------------------------------
// K0: weight transpose fp32 [K][N] -> bf16 [N][K]  (one-time, tiny)
// ---------------------------------------------------------------------------
__global__ __launch_bounds__(256) void wtrans(
    const float* __restrict__ w, unsigned short* __restrict__ wT,
    int K, int N) {
    __shared__ unsigned short lT[64][72];
    const int t = threadIdx.x;
    const int n0 = blockIdx.x * 64;   // output-row block (input col)
    const int k0 = blockIdx.y * 64;   // input-row block
#pragma unroll
    for (int i = 0; i < 4; i++) {     // read 64x64 fp32 tile, convert, transpose in LDS
        int idx = t + i * 256;
        int r = idx >> 4, c4 = (idx & 15) << 2;
        f32x4 v = *(const f32x4*)(w + (size_t)(k0 + r) * N + n0 + c4);
        lT[c4 + 0][r] = f2bf(v.x);
        lT[c4 + 1][r] = f2bf(v.y);
        lT[c4 + 2][r] = f2bf(v.z);
        lT[c4 + 3][r] = f2bf(v.w);
    }
    __syncthreads();
#pragma unroll
    for (int i = 0; i < 2; i++) {     // write 64 (n) x 64 (k) bf16, coalesced
        int idx = t + i * 256;
        int r2 = idx >> 3, s = idx & 7;
        s16x8 v8 = *(const s16x8*)(&lT[r2][s * 8]);
        *(s16x8*)(wT + (size_t)(n0 + r2) * K + k0 + s * 8) = v8;
    }
}

// ---------------------------------------------------------------------------
// K1: QKV GEMM.  x[32768][256] (fp32) @ w_qkvT[768][256] (bf16) + b ->
//     q/k/v bf16 in ws, layout [b][h][l][d]
// ---------------------------------------------------------------------------
__global__ __launch_bounds__(256) void qkv_gemm(
    const float* __restrict__ x, const unsigned short* __restrict__ wT,
    const float* __restrict__ bias, unsigned short* __restrict__ qkv) {
    __shared__ unsigned short lA[128][40];   // [row][k], pad 32->40 (80 B, /16 ok)
    __shared__ unsigned short lB[128][40];   // [col][k]
    const int t  = threadIdx.x;
    const int m0 = blockIdx.y * 128;
    const int n0 = blockIdx.x * 128;
    const int lane = t & 63, wv = t >> 6;
    const int wr = (wv >> 1) * 64, wc = (wv & 1) * 64;
    const int lr = lane & 15, lg = lane >> 4;

    f32x4 acc[4][4];
#pragma unroll
    for (int i = 0; i < 4; i++)
#pragma unroll
        for (int j = 0; j < 4; j++) acc[i][j] = f32x4{0.f, 0.f, 0.f, 0.f};

    for (int k0 = 0; k0 < 256; k0 += 32) {
#pragma unroll
        for (int i = 0; i < 4; i++) {               // A: 128x32 fp32 -> bf16, packed b64
            int idx = t + i * 256;
            int row = idx >> 3, c4 = (idx & 7) << 2;
            const f32x4 v = *(const f32x4*)(x + (size_t)(m0 + row) * 256 + k0 + c4);
            s16x4 b4;
            b4[0] = (short)f2bf(v.x); b4[1] = (short)f2bf(v.y);
            b4[2] = (short)f2bf(v.z); b4[3] = (short)f2bf(v.w);
            *(s16x4*)(&lA[row][c4]) = b4;
        }
#pragma unroll
        for (int i = 0; i < 2; i++) {               // B: 128x32 bf16 vector copy
            int idx = t + i * 256;
            int nn = idx >> 2, q = idx & 3;
            s16x8 v8 = *(const s16x8*)(wT + (size_t)(n0 + nn) * 256 + k0 + q * 8);
            *(s16x8*)(&lB[nn][q * 8]) = v8;
        }
        __syncthreads();
        s16x8 af[4], bf[4];
#pragma unroll
        for (int rt = 0; rt < 4; rt++) af[rt] = *(const s16x8*)(&lA[wr + rt * 16 + lr][lg * 8]);
#pragma unroll
        for (int ct = 0; ct < 4; ct++) bf[ct] = *(const s16x8*)(&lB[wc + ct * 16 + lr][lg * 8]);
#pragma unroll
        for (int rt = 0; rt < 4; rt++)
#pragma unroll
            for (int ct = 0; ct < 4; ct++)
                acc[rt][ct] = __builtin_amdgcn_mfma_f32_16x16x32_bf16(af[rt], bf[ct], acc[rt][ct], 0, 0, 0);
        __syncthreads();
    }
#pragma unroll
    for (int rt = 0; rt < 4; rt++)
#pragma unroll
        for (int ct = 0; ct < 4; ct++)
#pragma unroll
            for (int r = 0; r < 4; r++) {
                int gm = m0 + wr + rt * 16 + lg * 4 + r;
                int gn = n0 + wc + ct * 16 + lr;
                float val = acc[rt][ct][r] + bias[gn];
                int which = gn >> 8, h = (gn >> 5) & 7, d = gn & 31;
                int b = gm >> 8, ll = gm & 255;
                qkv[(size_t)which * QS + ((((size_t)b * NH + h) * L_ + ll) << 5) + d] = f2bf(val);
            }
}

// ---------------------------------------------------------------------------
// K2: fused attention per (b,h).  S=qk^T (MFMA), +mask, softmax (wave-parallel),
//     attn dump (nontemporal fp32), PV (MFMA), fused LePE conv, O -> ws bf16.
//     XCD-swizzled so same-b blocks share an XCD's L2 mask window.
// ---------------------------------------------------------------------------
__global__ __launch_bounds__(256) void attn_fused(
    const unsigned short* __restrict__ qw, const unsigned short* __restrict__ kw,
    const unsigned short* __restrict__ vw, const float* __restrict__ mask,
    const float* __restrict__ convw, const float* __restrict__ convb,
    float* __restrict__ attn_out, unsigned short* __restrict__ Ow) {
    __shared__ unsigned short lvT[32][264];  // v transposed: [d][l]
    __shared__ unsigned short lP[64][264];   // P bf16: [row(64)][col(256)]
    const int t = threadIdx.x;
    // bijective XCD swizzle: 1024 blocks = 8 XCDs x 128; co-resident blocks on
    // one XCD get consecutive bh -> shared mask window in that XCD's L2
    const int bh = ((blockIdx.x & 7) << 7) | (blockIdx.x >> 3);
    const int b = bh >> 3, h = bh & 7;
    const size_t base = (size_t)bh * (L_ * HD);
    const int lane = t & 63, wv = t >> 6;
    const int lr = lane & 15, lg = lane >> 4;
    const float scale = 0.17677669529663687f;  // 32^-0.5

    {   // stage v transposed into LDS
        const unsigned short* vrow = vw + base + (size_t)t * HD;
#pragma unroll
        for (int i = 0; i < 4; i++) {
            s16x8 v8 = *(const s16x8*)(vrow + i * 8);
#pragma unroll
            for (int j = 0; j < 8; j++) lvT[i * 8 + j][t] = (unsigned short)v8[j];
        }
    }
    __syncthreads();

    const float* mwin = mask + (size_t)(b & 63) * (256 * 256);

    for (int it = 0; it < 4; it++) {
        const int row0 = it * 64 + wv * 16;
        // ---- S = q @ k^T  (K=32, one MFMA per 16x16 tile)
        s16x8 qa = *(const s16x8*)(qw + base + (size_t)(row0 + lr) * HD + lg * 8);
        f32x4 sc[16];
        const f32x4 zero4 = f32x4{0.f, 0.f, 0.f, 0.f};
#pragma unroll
        for (int ct = 0; ct < 16; ct++) {
            s16x8 kb = *(const s16x8*)(kw + base + (size_t)(ct * 16 + lr) * HD + lg * 8);
            sc[ct] = __builtin_amdgcn_mfma_f32_16x16x32_bf16(qa, kb, zero4, 0, 0, 0);
        }
        // ---- scale + mask
        const int rbase = row0 + lg * 4;
#pragma unroll
        for (int r = 0; r < 4; r++) {
            const float* mrow = mwin + (size_t)(rbase + r) * 256 + lr;
#pragma unroll
            for (int ct = 0; ct < 16; ct++)
                sc[ct][r] = sc[ct][r] * scale + mrow[ct * 16];
        }
        // ---- softmax per row (row lives in 16 lanes sharing lg)
#pragma unroll
        for (int r = 0; r < 4; r++) {
            float mx = -1e30f;
#pragma unroll
            for (int ct = 0; ct < 16; ct++) mx = fmaxf(mx, sc[ct][r]);
#pragma unroll
            for (int off = 1; off < 16; off <<= 1) mx = fmaxf(mx, __shfl_xor(mx, off, 64));
            float sum = 0.f;
#pragma unroll
            for (int ct = 0; ct < 16; ct++) {
                float e = __expf(sc[ct][r] - mx);
                sc[ct][r] = e; sum += e;
            }
#pragma unroll
            for (int off = 1; off < 16; off <<= 1) sum += __shfl_xor(sum, off, 64);
            float inv = 1.f / sum;
#pragma unroll
            for (int ct = 0; ct < 16; ct++) sc[ct][r] *= inv;
        }
        // ---- P -> LDS (bf16)
#pragma unroll
        for (int ct = 0; ct < 16; ct++)
#pragma unroll
            for (int r = 0; r < 4; r++)
                lP[wv * 16 + lg * 4 + r][ct * 16 + lr] = f2bf(sc[ct][r]);
        __syncthreads();
        // ---- coalesced attn dump (nontemporal fp32 from bf16 P)
        {
            float* aout = attn_out + ((size_t)bh * 256 + it * 64) * 256;
#pragma unroll
            for (int i = 0; i < 16; i++) {
                int idx = t + i * 256;
                int r = idx >> 6, c4 = (idx & 63) << 2;
                s16x4 p4 = *(const s16x4*)(&lP[r][c4]);
                f32x4 o = f32x4{bf2f((unsigned short)p4[0]), bf2f((unsigned short)p4[1]),
                                bf2f((unsigned short)p4[2]), bf2f((unsigned short)p4[3])};
                __builtin_nontemporal_store(o, (f32x4*)(aout + (size_t)r * 256 + c4));
            }
        }
        // ---- PV: O(16x32) = P(16x256) @ v(256x32)
        f32x4 oacc[2];
        oacc[0] = f32x4{0.f, 0.f, 0.f, 0.f};
        oacc[1] = f32x4{0.f, 0.f, 0.f, 0.f};
#pragma unroll
        for (int ks = 0; ks < 8; ks++) {
            s16x8 pa = *(const s16x8*)(&lP[wv * 16 + lr][ks * 32 + lg * 8]);
#pragma unroll
            for (int dt = 0; dt < 2; dt++) {
                s16x8 vb = *(const s16x8*)(&lvT[dt * 16 + lr][ks * 32 + lg * 8]);
                oacc[dt] = __builtin_amdgcn_mfma_f32_16x16x32_bf16(pa, vb, oacc[dt], 0, 0, 0);
            }
        }
        // ---- LePE (depthwise 3x3 on v as (C,16,16)) + write O
#pragma unroll
        for (int dt = 0; dt < 2; dt++) {
            int d = dt * 16 + lr;
            int c = h * 32 + d;
            const float* w9 = convw + c * 9;
#pragma unroll
            for (int r = 0; r < 4; r++) {
                int lglob = row0 + lg * 4 + r;
                int y = lglob >> 4, xx = lglob & 15;
                float lep = convb[c];
#pragma unroll
                for (int dy = -1; dy <= 1; dy++) {
                    int yy = y + dy;
                    if (yy < 0 || yy > 15) continue;
#pragma unroll
                    for (int dx = -1; dx <= 1; dx++) {
                        int x2 = xx + dx;
                        if (x2 < 0 || x2 > 15) continue;
                        lep += w9[(dy + 1) * 3 + (dx + 1)] * bf2f(lvT[d][yy * 16 + x2]);
                    }
                }
                float ov = oacc[dt][r] + lep;
                Ow[((size_t)b * L_ + lglob) * C_ + c] = f2bf(ov);
            }
        }
        __syncthreads();   // protect lP before next iteration
    }
}

// ---------------------------------------------------------------------------
// K3: projection GEMM.  O[32768][256] (bf16 ws) @ w_projT[256][256] (bf16) + b -> out fp32
// ---------------------------------------------------------------------------
__global__ __launch_bounds__(256) void proj_gemm(
    const unsigned short* __restrict__ A, const unsigned short* __restrict__ wT,
    const float* __restrict__ bias, float* __restrict__ out) {
    __shared__ unsigned short lA[128][40];
    __shared__ unsigned short lB[128][40];
    const int t  = threadIdx.x;
    const int m0 = blockIdx.y * 128;
    const int n0 = blockIdx.x * 128;
    const int lane = t & 63, wv = t >> 6;
    const int wr = (wv >> 1) * 64, wc = (wv & 1) * 64;
    const int lr = lane & 15, lg = lane >> 4;

    f32x4 acc[4][4];
#pragma unroll
    for (int i = 0; i < 4; i++)
#pragma unroll
        for (int j = 0; j < 4; j++) acc[i][j] = f32x4{0.f, 0.f, 0.f, 0.f};

    for (int k0 = 0; k0 < 256; k0 += 32) {
#pragma unroll
        for (int i = 0; i < 2; i++) {              // A: 128x32 bf16
            int idx = t + i * 256;
            int row = idx >> 2, c8 = (idx & 3) << 3;
            s16x8 v8 = *(const s16x8*)(A + (size_t)(m0 + row) * 256 + k0 + c8);
            *(s16x8*)(&lA[row][c8]) = v8;
        }
#pragma unroll
        for (int i = 0; i < 2; i++) {              // B: 128x32 bf16 vector copy
            int idx = t + i * 256;
            int nn = idx >> 2, q = idx & 3;
            s16x8 v8 = *(const s16x8*)(wT + (size_t)(n0 + nn) * 256 + k0 + q * 8);
            *(s16x8*)(&lB[nn][q * 8]) = v8;
        }
        __syncthreads();
        s16x8 af[4], bf[4];
#pragma unroll
        for (int rt = 0; rt < 4; rt++) af[rt] = *(const s16x8*)(&lA[wr + rt * 16 + lr][lg * 8]);
#pragma unroll
        for (int ct = 0; ct < 4; ct++) bf[ct] = *(const s16x8*)(&lB[wc + ct * 16 + lr][lg * 8]);
#pragma unroll
        for (int rt = 0; rt < 4; rt++)
#pragma unroll
            for (int ct = 0; ct < 4; ct++)
                acc[rt][ct] = __builtin_amdgcn_mfma_f32_16x16x32_bf16(af[rt], bf[ct], acc[rt][ct], 0, 0, 0);
        __syncthreads();
    }
#pragma unroll
    for (int rt = 0; rt < 4; rt++)
#pragma unroll
        for (int ct = 0; ct < 4; ct++)
#pragma unroll
            for (int r = 0; r < 4; r++) {
                int gm = m0 + wr + rt * 16 + lg * 4 + r;
                int gn = n0 + wc + ct * 16 + lr;
                out[(size_t)gm * 256 + gn] = acc[rt][ct][r] + bias[gn];
            }
}

// ---------------------------------------------------------------------------
extern "C" void kernel_launch(void* const* d_in, const int* in_sizes, int n_in,
                              void* d_out, int out_size, void* d_ws, size_t ws_size,
                              hipStream_t stream) {
    const float* x      = (const float*)d_in[0];
    const float* mask   = (const float*)d_in[1];
    const float* w_qkv  = (const float*)d_in[2];
    const float* b_qkv  = (const float*)d_in[3];
    const float* conv_w = (const float*)d_in[4];
    const float* conv_b = (const float*)d_in[5];
    const float* w_proj = (const float*)d_in[6];
    const float* b_proj = (const float*)d_in[7];

    float* out  = (float*)d_out;
    float* attn = out + (size_t)MTOT * C_;          // second output, concatenated

    unsigned short* ws = (unsigned short*)d_ws;     // 64 MB + 640 KB of ws used
    unsigned short* qw     = ws;
    unsigned short* kw     = ws + (size_t)QS;
    unsigned short* vw     = ws + (size_t)2 * QS;
    unsigned short* Ow     = ws + (size_t)3 * QS;
    unsigned short* wqkvT  = ws + (size_t)4 * QS;               // 768x256 bf16
    unsigned short* wprojT = ws + (size_t)4 * QS + NQKV * C_;   // 256x256 bf16

    wtrans<<<dim3(12, 4), 256, 0, stream>>>(w_qkv, wqkvT, C_, NQKV);
    wtrans<<<dim3(4, 4), 256, 0, stream>>>(w_proj, wprojT, C_, C_);
    qkv_gemm<<<dim3(6, 256), 256, 0, stream>>>(x, wqkvT, b_qkv, qw);
    attn_fused<<<dim3(1024), 256, 0, stream>>>(qw, kw, vw, mask, conv_w, conv_b, attn, Ow);
    proj_gemm<<<dim3(2, 256), 256, 0, stream>>>(Ow, wprojT, b_proj, out);
}